// Round 9
// baseline (185.374 us; speedup 1.0000x reference)
//
#include <hip/hip_runtime.h>
#include <math.h>

#define D 256
#define S 4096
#define H 8
#define DH 32
#define DM 1024
#define NTOK 8192   // B*S

typedef __attribute__((ext_vector_type(8))) short short8;
typedef __attribute__((ext_vector_type(4))) float f32x4;

// qscale = (1/sqrt(32)) * log2(e): folds softmax scale + exp->exp2 into Q
#define QSCALE (0.17677669529663687f * 1.4426950408889634f)

__device__ inline unsigned short f2bf(float f) {
    union { float f; unsigned u; } v; v.f = f;
    unsigned r = v.u + 0x7fffu + ((v.u >> 16) & 1u);
    return (unsigned short)(r >> 16);
}
__device__ inline void gload16(const void* g, void* l) {
    __builtin_amdgcn_global_load_lds((const __attribute__((address_space(1))) void*)g,
                                     (__attribute__((address_space(3))) void*)l, 16, 0, 0);
}

// exp2 + truncate-to-bf16 pack of two f32x4 score vectors into one B-fragment.
// Truncation (not RNE) is fine: the bias cancels between numerator and the
// ones-MFMA denominator, which sums the SAME truncated bf16 P values.
__device__ inline short8 pack_p(f32x4 s0, f32x4 s1) {
    unsigned u0[4], u1[4];
    #pragma unroll
    for (int i = 0; i < 4; ++i) {
        union { float f; unsigned u; } c0, c1;
        c0.f = __builtin_amdgcn_exp2f(s0[i]);
        c1.f = __builtin_amdgcn_exp2f(s1[i]);
        u0[i] = c0.u;
        u1[i] = c1.u;
    }
    union { unsigned u[4]; short8 s; } pk;
    pk.u[0] = __builtin_amdgcn_perm(u0[1], u0[0], 0x07060302u);
    pk.u[1] = __builtin_amdgcn_perm(u0[3], u0[2], 0x07060302u);
    pk.u[2] = __builtin_amdgcn_perm(u1[1], u1[0], 0x07060302u);
    pk.u[3] = __builtin_amdgcn_perm(u1[3], u1[2], 0x07060302u);
    return pk.s;
}

// ---- prep: weights fp32->bf16 + RoPE table + LayerNorm1, ONE launch ----
// blocks 0..3327: conversion/table; blocks 3328..5375: LN1 (1 wave = 1 row).
__global__ void prep(const float* __restrict__ Wq, const float* __restrict__ Wk,
                     const float* __restrict__ Wv, const float* __restrict__ Wo,
                     const float* __restrict__ W2, const float* __restrict__ W3,
                     unsigned short* __restrict__ wqkv, unsigned short* __restrict__ wo_b,
                     unsigned short* __restrict__ w2_b, unsigned short* __restrict__ w3_b,
                     float* __restrict__ ct, float* __restrict__ st,
                     const float* __restrict__ x, const float* __restrict__ g,
                     const float* __restrict__ b, unsigned short* __restrict__ xn) {
    int blk = blockIdx.x;
    if (blk < 3328) {
        int i = blk * 256 + threadIdx.x;           // 0 .. 851967
        if (i < 196608) {
            const float* s = (i < 65536) ? Wq : ((i < 131072) ? Wk : Wv);
            wqkv[i] = f2bf(s[i & 65535]);
        } else if (i < 262144) {
            wo_b[i - 196608] = f2bf(Wo[i - 196608]);
        } else if (i < 524288) {
            w2_b[i - 262144] = f2bf(W2[i - 262144]);
        } else if (i < 786432) {
            w3_b[i - 524288] = f2bf(W3[i - 524288]);
        } else {
            int j = i - 786432;                     // 0 .. 65535
            int spos = j >> 4, pi = j & 15;
            float inv_freq = powf(10000.0f, -(float)(2 * pi) / 32.0f);
            float fr = (float)spos * inv_freq;
            ct[j] = cosf(fr);
            st[j] = sinf(fr);
        }
        return;
    }
    // LayerNorm1: 1 wave = 1 row, float4/lane, no LDS/barriers
    int l = threadIdx.x & 63;
    int row = (blk - 3328) * 4 + (threadIdx.x >> 6);
    const float4 v = *(const float4*)(x + (size_t)row * D + l * 4);
    float s  = v.x + v.y + v.z + v.w;
    float s2 = v.x * v.x + v.y * v.y + v.z * v.z + v.w * v.w;
    #pragma unroll
    for (int off = 32; off > 0; off >>= 1) {
        s  += __shfl_xor(s, off, 64);
        s2 += __shfl_xor(s2, off, 64);
    }
    float mu  = s * (1.0f / D);
    float var = s2 * (1.0f / D) - mu * mu;
    float rs  = rsqrtf(var + 1e-5f);
    const float4 gg = *(const float4*)(g + l * 4);
    const float4 bb = *(const float4*)(b + l * 4);
    ushort4 o;
    o.x = f2bf((v.x - mu) * rs * gg.x + bb.x);
    o.y = f2bf((v.y - mu) * rs * gg.y + bb.y);
    o.z = f2bf((v.z - mu) * rs * gg.z + bb.z);
    o.w = f2bf((v.w - mu) * rs * gg.w + bb.w);
    *(ushort4*)(xn + (size_t)row * D + l * 4) = o;
}

// ---------------- LayerNorm: 1 wave = 1 row, float4/lane (for LN2) ----------------
__global__ void ln_kernel(const float* __restrict__ x, const float* __restrict__ g,
                          const float* __restrict__ b, unsigned short* __restrict__ out) {
    int l = threadIdx.x & 63;
    int row = blockIdx.x * 4 + (threadIdx.x >> 6);
    const float4 v = *(const float4*)(x + (size_t)row * D + l * 4);
    float s  = v.x + v.y + v.z + v.w;
    float s2 = v.x * v.x + v.y * v.y + v.z * v.z + v.w * v.w;
    #pragma unroll
    for (int off = 32; off > 0; off >>= 1) {
        s  += __shfl_xor(s, off, 64);
        s2 += __shfl_xor(s2, off, 64);
    }
    float mu  = s * (1.0f / D);
    float var = s2 * (1.0f / D) - mu * mu;
    float rs  = rsqrtf(var + 1e-5f);
    const float4 gg = *(const float4*)(g + l * 4);
    const float4 bb = *(const float4*)(b + l * 4);
    ushort4 o;
    o.x = f2bf((v.x - mu) * rs * gg.x + bb.x);
    o.y = f2bf((v.y - mu) * rs * gg.y + bb.y);
    o.z = f2bf((v.z - mu) * rs * gg.z + bb.z);
    o.w = f2bf((v.w - mu) * rs * gg.w + bb.w);
    *(ushort4*)(out + (size_t)row * D + l * 4) = o;
}

// ------- bf16 MFMA GEMM, 64x64 tile, BK=64 dbuf (R5-proven for wide-N GEMMs) -------
// R22 lesson: 128x64 tile regressed these K=256 GEMMs (3 blocks/CU vs 6; 4 K-iters
// too short to amortize) — 64x64 with 6 blocks/CU is the sweet spot here.
// modes: 0 = QKV: RoPE+store bf16 for cols<512 (Q cols<256 pre-scaled), cols>=512
//            stored TRANSPOSED to vt[B][H][DH][S];  2 = bf16 store gelu(acc+bias)
__global__ __launch_bounds__(256) void gemm64b(const unsigned short* __restrict__ A,
        const unsigned short* __restrict__ Bw, void* __restrict__ outp,
        unsigned short* __restrict__ vt,
        const float* __restrict__ bias,
        const float* __restrict__ ct, const float* __restrict__ st,
        int N, int K, int mode) {
    __shared__ unsigned short As[2][64 * 64];
    __shared__ unsigned short Bs[2][64 * 64];
    int tid = threadIdx.x;
    int w = tid >> 6, l = tid & 63;
    int lm = l & 15, lg = l >> 4;
    int wm = (w >> 1) * 32, wn = (w & 1) * 32;
    int bm = blockIdx.x * 64, bn = blockIdx.y * 64;
    int r1 = tid >> 3, pc = tid & 7;
    int pcx = (pc ^ (r1 & 7)) * 8;
    const unsigned short* Ag1 = A + (size_t)(bm + r1) * K + pcx;
    const unsigned short* Ag2 = A + (size_t)(bm + 32 + r1) * K + pcx;
    const unsigned short* Bg1 = Bw + (size_t)(bn + r1) * K + pcx;
    const unsigned short* Bg2 = Bw + (size_t)(bn + 32 + r1) * K + pcx;
    const int swz = lm & 7;
    f32x4 acc[2][2] = {};

    gload16(Ag1, &As[0][w * 512]);
    gload16(Ag2, &As[0][2048 + w * 512]);
    gload16(Bg1, &Bs[0][w * 512]);
    gload16(Bg2, &Bs[0][2048 + w * 512]);
    for (int k0 = 0; k0 < K; k0 += 64) {
        int cur = (k0 >> 6) & 1;
        __syncthreads();
        if (k0 + 64 < K) {
            gload16(Ag1 + k0 + 64, &As[1 - cur][w * 512]);
            gload16(Ag2 + k0 + 64, &As[1 - cur][2048 + w * 512]);
            gload16(Bg1 + k0 + 64, &Bs[1 - cur][w * 512]);
            gload16(Bg2 + k0 + 64, &Bs[1 - cur][2048 + w * 512]);
        }
        #pragma unroll
        for (int j = 0; j < 2; ++j) {
            int ch = ((j * 4 + lg) ^ swz) * 8;
            short8 af[2], bf[2];
            #pragma unroll
            for (int i = 0; i < 2; ++i) af[i] = *(const short8*)&As[cur][(wm + i * 16 + lm) * 64 + ch];
            #pragma unroll
            for (int i = 0; i < 2; ++i) bf[i] = *(const short8*)&Bs[cur][(wn + i * 16 + lm) * 64 + ch];
            #pragma unroll
            for (int mi = 0; mi < 2; ++mi)
                #pragma unroll
                for (int ni = 0; ni < 2; ++ni)
                    acc[mi][ni] = __builtin_amdgcn_mfma_f32_16x16x32_bf16(af[mi], bf[ni], acc[mi][ni], 0, 0, 0);
        }
    }

    if (mode == 0) {
        if (bn >= 512) {
            #pragma unroll
            for (int mi = 0; mi < 2; ++mi) {
                #pragma unroll
                for (int ni = 0; ni < 2; ++ni) {
                    int ng = bn + wn + ni * 16 + lm - 512;   // h*32+dh
                    int hh = ng >> 5, dh = ng & 31;
                    int mg0 = bm + wm + mi * 16 + lg * 4;
                    int bbx = mg0 >> 12, ss = mg0 & 4095;
                    ushort4 pv;
                    pv.x = f2bf(acc[mi][ni][0]); pv.y = f2bf(acc[mi][ni][1]);
                    pv.z = f2bf(acc[mi][ni][2]); pv.w = f2bf(acc[mi][ni][3]);
                    *(ushort4*)(vt + ((size_t)((bbx * 8 + hh) * 32 + dh)) * S + ss) = pv;
                }
            }
        } else {
            #pragma unroll
            for (int mi = 0; mi < 2; ++mi) {
                #pragma unroll
                for (int ni = 0; ni < 2; ++ni) {
                    int ng = bn + wn + ni * 16 + lm;
                    int pi = (ng & 31) >> 1;
                    float sgn = (ng & 1) ? 1.f : -1.f;
                    float qs  = (ng < 256) ? QSCALE : 1.f;
                    #pragma unroll
                    for (int r2 = 0; r2 < 4; ++r2) {
                        int mg = bm + wm + mi * 16 + lg * 4 + r2;
                        int spos = mg & (S - 1);
                        float vv = acc[mi][ni][r2];
                        float pv = __shfl_xor(vv, 1, 64);
                        float cs = ct[spos * 16 + pi];
                        float sn = st[spos * 16 + pi];
                        float ov = (vv * cs + sgn * pv * sn) * qs;
                        ((unsigned short*)outp)[(size_t)mg * N + ng] = f2bf(ov);
                    }
                }
            }
        }
        return;
    }
    // mode 2: gelu(acc+bias), bf16 store
    #pragma unroll
    for (int mi = 0; mi < 2; ++mi) {
        #pragma unroll
        for (int ni = 0; ni < 2; ++ni) {
            int ng = bn + wn + ni * 16 + lm;
            #pragma unroll
            for (int r2 = 0; r2 < 4; ++r2) {
                int mg = bm + wm + mi * 16 + lg * 4 + r2;
                float t = acc[mi][ni][r2] + bias[ng];
                ((unsigned short*)outp)[(size_t)mg * N + ng] =
                    f2bf(0.5f * t * (1.0f + erff(t * 0.70710678118654752f)));
            }
        }
    }
}

// ------- bf16 MFMA GEMM v3, 64x64 tile, BK=64 x 3-buf counted-vmcnt (R25) -------
// R25: port of the attn-proven R19 pipeline to the N=256 GEMMs. Old v2 (BK=128
// dbuf) paid a full vmcnt(0)+barrier drain every 128 K-elems (8 drains at
// K=1024). v3: 3 buffer sets, depth-2 prefetch, raw s_barrier with counted
// "s_waitcnt vmcnt(4) lgkmcnt(0)" — next tile's 4 loads stay in flight across
// the barrier with a full compute phase to land. Same WAR proof as attn: buffer
// written at step J was last read at step J-1; lgkmcnt(0)+barrier retires those
// reads block-wide before any wave issues DMA. LDS 64->48KB. Dummy clamped
// prefetches keep vmcnt uniform; trailing vmcnt(0) drains them before exit.
// modes: 1 = fp32 store acc+res; 3 = fp32 store acc+bias+res
__global__ __launch_bounds__(256) void gemm32(const unsigned short* __restrict__ A,
        const unsigned short* __restrict__ Bw, void* __restrict__ outp,
        const float* __restrict__ bias, const float* __restrict__ res,
        int N, int K, int mode) {
    __shared__ unsigned short As[3][64 * 64];   // 24KB
    __shared__ unsigned short Bs[3][64 * 64];   // 24KB
    int tid = threadIdx.x;
    int w = tid >> 6, l = tid & 63;
    int lm = l & 15, lg = l >> 4;
    int wm = (w >> 1) * 32, wn = (w & 1) * 32;
    int bm = blockIdx.x * 64, bn = blockIdx.y * 64;
    int r1 = tid >> 3, pc = tid & 7;
    int pcx = (pc ^ (r1 & 7)) * 8;
    const unsigned short* Ag1 = A + (size_t)(bm + r1) * K + pcx;
    const unsigned short* Ag2 = A + (size_t)(bm + 32 + r1) * K + pcx;
    const unsigned short* Bg1 = Bw + (size_t)(bn + r1) * K + pcx;
    const unsigned short* Bg2 = Bw + (size_t)(bn + 32 + r1) * K + pcx;
    const int swz = lm & 7;
    f32x4 acc[2][2] = {};
    const int nk = K >> 6;                      // 4 (K=256) or 16 (K=1024)

    // depth-2 prologue: tile0 -> buf0, tile1 -> buf1 (4 loads each)
    gload16(Ag1,      &As[0][w * 512]);
    gload16(Ag2,      &As[0][2048 + w * 512]);
    gload16(Bg1,      &Bs[0][w * 512]);
    gload16(Bg2,      &Bs[0][2048 + w * 512]);
    gload16(Ag1 + 64, &As[1][w * 512]);
    gload16(Ag2 + 64, &As[1][2048 + w * 512]);
    gload16(Bg1 + 64, &Bs[1][w * 512]);
    gload16(Bg2 + 64, &Bs[1][2048 + w * 512]);

    for (int it = 0; it < nk; ++it) {
        int cur = it % 3;
        int nxt = (it + 2) % 3;
        asm volatile("s_waitcnt vmcnt(4) lgkmcnt(0)" ::: "memory");
        __builtin_amdgcn_s_barrier();
        __builtin_amdgcn_sched_barrier(0);
        int tn = it + 2; if (tn > nk - 1) tn = nk - 1;   // clamped dummy prefetch
        int ko = tn << 6;
        gload16(Ag1 + ko, &As[nxt][w * 512]);
        gload16(Ag2 + ko, &As[nxt][2048 + w * 512]);
        gload16(Bg1 + ko, &Bs[nxt][w * 512]);
        gload16(Bg2 + ko, &Bs[nxt][2048 + w * 512]);
        #pragma unroll
        for (int j = 0; j < 2; ++j) {
            int ch = ((j * 4 + lg) ^ swz) * 8;
            short8 af[2], bf[2];
            #pragma unroll
            for (int i = 0; i < 2; ++i) af[i] = *(const short8*)&As[cur][(wm + i * 16 + lm) * 64 + ch];
            #pragma unroll
            for (int i = 0; i < 2; ++i) bf[i] = *(const short8*)&Bs[cur][(wn + i * 16 + lm) * 64 + ch];
            #pragma unroll
            for (int mi = 0; mi < 2; ++mi)
                #pragma unroll
                for (int ni = 0; ni < 2; ++ni)
                    acc[mi][ni] = __builtin_amdgcn_mfma_f32_16x16x32_bf16(af[mi], bf[ni], acc[mi][ni], 0, 0, 0);
        }
    }
    asm volatile("s_waitcnt vmcnt(0)" ::: "memory");   // drain dummy prefetch DMAs

    #pragma unroll
    for (int mi = 0; mi < 2; ++mi) {
        #pragma unroll
        for (int ni = 0; ni < 2; ++ni) {
            int ng = bn + wn + ni * 16 + lm;
            #pragma unroll
            for (int r2 = 0; r2 < 4; ++r2) {
                int mg = bm + wm + mi * 16 + lg * 4 + r2;
                float v = acc[mi][ni][r2];
                size_t idx = (size_t)mg * N + ng;
                if (mode == 1) {
                    ((float*)outp)[idx] = v + res[idx];
                } else {
                    ((float*)outp)[idx] = v + bias[ng] + res[idx];
                }
            }
        }
    }
}

// -------- MFMA flash attention: R19 structure + cross-half pipelining (R24) ------
// Pinned at 48.0-48.1us across 6 structural variants (R19/R23/R24 etc);
// MfmaUtil+VALUBusy ~80% combined — structural floor for this decomposition.
// R23 lesson: more occupancy does NOT help (split-key x4 +45% waves = net worse).
// R20 lesson: LDS staging via global_load_lds DMA is the transaction-efficient
// shape; per-lane fragment gathers split ~16x.
__global__ __launch_bounds__(512, 4) void attn_kernel(const unsigned short* __restrict__ Cq,
        const unsigned short* __restrict__ vt, unsigned short* __restrict__ out) {
    __shared__ unsigned short Ks[2][3][64][32];  // [grp][buf][phys key row][dim] 24KB
    __shared__ unsigned short Vs[2][3][32][64];  // [grp][buf][dim][key]          24KB
    int tid = threadIdx.x;
    int w = tid >> 6, l = tid & 63;
    int grp = w >> 2, ws = w & 3;
    int lm = l & 15, lg = l >> 4;
    int qt = blockIdx.x >> 4;                    // XCD-cluster swizzle
    int bh = blockIdx.x & 15;
    int bb = bh >> 3, h = bh & 7;
    int q0 = qt * 128 + ws * 32;                 // 32 q rows per wave

    const short8 qfa = *(const short8*)(Cq + ((size_t)(bb * S + q0 + lm)) * 768 + h * DH + lg * 8);
    const short8 qfb = *(const short8*)(Cq + ((size_t)(bb * S + q0 + 16 + lm)) * 768 + h * DH + lg * 8);

    // ones A-fragment in registers: A row 0 = 1.0 -> lanes with lm==0, any k-col
    union { unsigned short us[8]; short8 s; } onesu;
    {
        unsigned short ov = (lm == 0) ? (unsigned short)0x3F80 : (unsigned short)0;
        #pragma unroll
        for (int i = 0; i < 8; ++i) onesu.us[i] = ov;
    }
    const short8 onef = onesu.s;

    int p = ws * 16 + (l >> 2);
    int krow = ((p >> 5) << 5) + (((p >> 2) & 3) << 3) + (((p >> 4) & 1) << 2) + (p & 3);
    const unsigned short* kg = Cq + ((size_t)(bb * S)) * 768 + 256 + h * 32
                               + (size_t)krow * 768 + ((l & 3) ^ ((l >> 3) & 3)) * 8;
    const unsigned short* vg = vt + ((size_t)(bh * 32 + ws * 8 + (l >> 3))) * S + ((l & 7) ^ (l >> 3)) * 8;
    const int kswz = (lm >> 1) & 3;
    const int vswz = lm & 7;

    f32x4 o0a = {0.f, 0.f, 0.f, 0.f}, o1a = {0.f, 0.f, 0.f, 0.f}, o2a = {0.f, 0.f, 0.f, 0.f};
    f32x4 o0b = {0.f, 0.f, 0.f, 0.f}, o1b = {0.f, 0.f, 0.f, 0.f}, o2b = {0.f, 0.f, 0.f, 0.f};
    const f32x4 z = {0.f, 0.f, 0.f, 0.f};

    // depth-2 prologue: tiles grp -> buf0, 2+grp -> buf1 (K,V per tile; 4 loads)
    gload16(kg + (size_t)grp * 64 * 768,       &Ks[grp][0][ws * 16][0]);
    gload16(vg + (size_t)grp * 64,             &Vs[grp][0][ws * 8][0]);
    gload16(kg + (size_t)(2 + grp) * 64 * 768, &Ks[grp][1][ws * 16][0]);
    gload16(vg + (size_t)(2 + grp) * 64,       &Vs[grp][1][ws * 8][0]);
    // fence: Q register loads retired; exactly 4 stage loads outstanding
    asm volatile("s_waitcnt vmcnt(4)" ::: "memory");

#define ATTN_STEP(J, CUR, NXT) do {                                                          \
    asm volatile("s_waitcnt vmcnt(2) lgkmcnt(0)" ::: "memory");                              \
    __builtin_amdgcn_s_barrier();                                                            \
    __builtin_amdgcn_sched_barrier(0);                                                       \
    int tt_ = (J) + 2; if (tt_ > 31) tt_ = 31;                                               \
    size_t tg_ = (size_t)(2 * tt_ + grp);                                                    \
    gload16(kg + tg_ * 64 * 768, &Ks[grp][NXT][ws * 16][0]);                                 \
    gload16(vg + tg_ * 64,       &Vs[grp][NXT][ws * 8][0]);                                  \
    short8 kf0 = *(const short8*)&Ks[grp][CUR][lm][(lg ^ kswz) * 8];                         \
    short8 kf1 = *(const short8*)&Ks[grp][CUR][16 + lm][(lg ^ kswz) * 8];                    \
    short8 kf2 = *(const short8*)&Ks[grp][CUR][32 + lm][(lg ^ kswz) * 8];                    \
    short8 kf3 = *(const short8*)&Ks[grp][CUR][48 + lm][(lg ^ kswz) * 8];                    \
    __builtin_amdgcn_s_setprio(1);                                                           \
    f32x4 s0a = __builtin_amdgcn_mfma_f32_16x16x32_bf16(kf0, qfa, z, 0, 0, 0);               \
    f32x4 s1a = __builtin_amdgcn_mfma_f32_16x16x32_bf16(kf1, qfa, z, 0, 0, 0);               \
    f32x4 s0b = __builtin_amdgcn_mfma_f32_16x16x32_bf16(kf0, qfb, z, 0, 0, 0);               \
    f32x4 s1b = __builtin_amdgcn_mfma_f32_16x16x32_bf16(kf1, qfb, z, 0, 0, 0);               \
    f32x4 t0a = __builtin_amdgcn_mfma_f32_16x16x32_bf16(kf2, qfa, z, 0, 0, 0);               \
    f32x4 t1a = __builtin_amdgcn_mfma_f32_16x16x32_bf16(kf3, qfa, z, 0, 0, 0);               \
    f32x4 t0b = __builtin_amdgcn_mfma_f32_16x16x32_bf16(kf2, qfb, z, 0, 0, 0);               \
    f32x4 t1b = __builtin_amdgcn_mfma_f32_16x16x32_bf16(kf3, qfb, z, 0, 0, 0);               \
    __builtin_amdgcn_s_setprio(0);                                                           \
    short8 pfa = pack_p(s0a, s1a);                                                           \
    short8 pfb = pack_p(s0b, s1b);                                                           \
    int vc0 = (lg ^ vswz) * 8;                                                               \
    short8 va0 = *(const short8*)&Vs[grp][CUR][lm][vc0];                                     \
    short8 va1 = *(const short8*)&Vs[grp][CUR][16 + lm][vc0];                                \
    __builtin_amdgcn_s_setprio(1);                                                           \
    o0a = __builtin_amdgcn_mfma_f32_16x16x32_bf16(va0, pfa, o0a, 0, 0, 0);                   \
    o1a = __builtin_amdgcn_mfma_f32_16x16x32_bf16(va1, pfa, o1a, 0, 0, 0);                   \
    o2a = __builtin_amdgcn_mfma_f32_16x16x32_bf16(onef, pfa, o2a, 0, 0, 0);                  \
    o0b = __builtin_amdgcn_mfma_f32_16x16x32_bf16(va0, pfb, o0b, 0, 0, 0);                   \
    o1b = __builtin_amdgcn_mfma_f32_16x16x32_bf16(va1, pfb, o1b, 0, 0, 0);                   \
    o2b = __builtin_amdgcn_mfma_f32_16x16x32_bf16(onef, pfb, o2b, 0, 0, 0);                  \
    __builtin_amdgcn_s_setprio(0);                                                           \
    short8 pfa2 = pack_p(t0a, t1a);                                                          \
    short8 pfb2 = pack_p(t0b, t1b);                                                          \
    int vc1 = ((4 + lg) ^ vswz) * 8;                                                         \
    short8 vb0 = *(const short8*)&Vs[grp][CUR][lm][vc1];                                     \
    short8 vb1 = *(const short8*)&Vs[grp][CUR][16 + lm][vc1];                                \
    __builtin_amdgcn_s_setprio(1);                                                           \
    o0a = __builtin_amdgcn_mfma_f32_16x16x32_bf16(vb0, pfa2, o0a, 0, 0, 0);                  \
    o1a = __builtin_amdgcn_mfma_f32_16x16x32_bf16(vb1, pfa2, o1a, 0, 0, 0);                  \
    o2a = __builtin_amdgcn_mfma_f32_16x16x32_bf16(onef, pfa2, o2a, 0, 0, 0);                 \
    o0b = __builtin_amdgcn_mfma_f32_16x16x32_bf16(vb0, pfb2, o0b, 0, 0, 0);                  \
    o1b = __builtin_amdgcn_mfma_f32_16x16x32_bf16(vb1, pfb2, o1b, 0, 0, 0);                  \
    o2b = __builtin_amdgcn_mfma_f32_16x16x32_bf16(onef, pfb2, o2b, 0, 0, 0);                 \
    __builtin_amdgcn_s_setprio(0);                                                           \
} while (0)

    for (int j3 = 0; j3 < 30; j3 += 3) {
        ATTN_STEP(j3,     0, 2);
        ATTN_STEP(j3 + 1, 1, 0);
        ATTN_STEP(j3 + 2, 2, 1);
    }
    ATTN_STEP(30, 0, 2);
    ATTN_STEP(31, 1, 0);
#undef ATTN_STEP

    // cross-group combine via LDS aliased onto the (now dead) staging buffers
    f32x4* Red = (f32x4*)&Ks[0][0][0][0];   // 4acc x 4ws x 64l x 16B = 16KB (of 24KB)
    float* Den = (float*)&Vs[0][0][0][0];   // 4ws x 2 x 64l x 4B = 2KB
    __syncthreads();                        // drains dummy prefetches too (vmcnt 0)
    if (grp) {
        Red[(0 * 4 + ws) * 64 + l] = o0a;
        Red[(1 * 4 + ws) * 64 + l] = o1a;
        Red[(2 * 4 + ws) * 64 + l] = o0b;
        Red[(3 * 4 + ws) * 64 + l] = o1b;
        Den[(ws * 2 + 0) * 64 + l] = o2a[0];
        Den[(ws * 2 + 1) * 64 + l] = o2b[0];
    }
    __syncthreads();
    if (!grp) {
        f32x4 a0 = Red[(0 * 4 + ws) * 64 + l];
        f32x4 a1 = Red[(1 * 4 + ws) * 64 + l];
        f32x4 a2 = Red[(2 * 4 + ws) * 64 + l];
        f32x4 a3 = Red[(3 * 4 + ws) * 64 + l];
        float dda = o2a[0] + Den[(ws * 2 + 0) * 64 + l];
        float ddb = o2b[0] + Den[(ws * 2 + 1) * 64 + l];
        #pragma unroll
        for (int i = 0; i < 4; ++i) {
            o0a[i] += a0[i]; o1a[i] += a1[i];
            o0b[i] += a2[i]; o1b[i] += a3[i];
        }
        float inva = 1.0f / __shfl(dda, lm, 64);
        float invb = 1.0f / __shfl(ddb, lm, 64);
        ushort4 r0, r1;
        r0.x = f2bf(o0a[0] * inva); r0.y = f2bf(o0a[1] * inva);
        r0.z = f2bf(o0a[2] * inva); r0.w = f2bf(o0a[3] * inva);
        r1.x = f2bf(o1a[0] * inva); r1.y = f2bf(o1a[1] * inva);
        r1.z = f2bf(o1a[2] * inva); r1.w = f2bf(o1a[3] * inva);
        unsigned short* ob = out + ((size_t)(bb * S + q0 + lm)) * D + h * DH;
        *(ushort4*)(ob + lg * 4)      = r0;
        *(ushort4*)(ob + 16 + lg * 4) = r1;
        r0.x = f2bf(o0b[0] * invb); r0.y = f2bf(o0b[1] * invb);
        r0.z = f2bf(o0b[2] * invb); r0.w = f2bf(o0b[3] * invb);
        r1.x = f2bf(o1b[0] * invb); r1.y = f2bf(o1b[1] * invb);
        r1.z = f2bf(o1b[2] * invb); r1.w = f2bf(o1b[3] * invb);
        unsigned short* ob2 = out + ((size_t)(bb * S + q0 + 16 + lm)) * D + h * DH;
        *(ushort4*)(ob2 + lg * 4)      = r0;
        *(ushort4*)(ob2 + 16 + lg * 4) = r1;
    }
}

extern "C" void kernel_launch(void* const* d_in, const int* in_sizes, int n_in,
                              void* d_out, int out_size, void* d_ws, size_t ws_size,
                              hipStream_t stream) {
    const float* x     = (const float*)d_in[0];
    const float* Wq    = (const float*)d_in[1];
    const float* Wk    = (const float*)d_in[2];
    const float* Wv    = (const float*)d_in[3];
    const float* Wo    = (const float*)d_in[4];
    const float* ln1_g = (const float*)d_in[5];
    const float* ln1_b = (const float*)d_in[6];
    const float* ln2_g = (const float*)d_in[7];
    const float* ln2_b = (const float*)d_in[8];
    const float* W2    = (const float*)d_in[9];
    const float* b2    = (const float*)d_in[10];
    const float* W3    = (const float*)d_in[11];
    const float* b3    = (const float*)d_in[12];

    char* w8 = (char*)d_ws;
    unsigned short* wqkv = (unsigned short*)(w8);             // 196608 ush
    unsigned short* wo_b = (unsigned short*)(w8 + 393216);    // 65536
    unsigned short* w2_b = (unsigned short*)(w8 + 524288);    // 262144
    unsigned short* w3_b = (unsigned short*)(w8 + 1048576);   // 262144
    float*          ct   = (float*)(w8 + 1572864);            // 65536 f32
    float*          st   = (float*)(w8 + 1835008);            // 65536 f32
    unsigned short* xn   = (unsigned short*)(w8 + 2097152);   // 2M ush (reused as yn)
    unsigned short* Cq   = (unsigned short*)(w8 + 6291456);   // 6.29M ush (QKV out)
    unsigned short* hb   = Cq;                                // MLP hidden reuses (16MB)
    unsigned short* vtb  = (unsigned short*)(w8 + 23068672);  // 2M ush
    unsigned short* ab   = (unsigned short*)(w8 + 27262976);  // 2M ush
    float*          mlpin= (float*)(w8 + 31457280);           // 2M f32
    unsigned short* yn   = xn;

    prep<<<5376, 256, 0, stream>>>(Wq, Wk, Wv, Wo, W2, W3, wqkv, wo_b, w2_b, w3_b,
                                   ct, st, x, ln1_g, ln1_b, xn);
    gemm64b<<<dim3(128, 12), 256, 0, stream>>>(xn, wqkv, Cq, vtb, nullptr, ct, st, 768, 256, 0);
    attn_kernel<<<512, 512, 0, stream>>>(Cq, vtb, ab);
    gemm32<<<dim3(128, 4), 256, 0, stream>>>(ab, wo_b, mlpin, nullptr, x, 256, 256, 1);
    ln_kernel<<<NTOK / 4, 256, 0, stream>>>(mlpin, ln2_g, ln2_b, yn);
    gemm64b<<<dim3(128, 16), 256, 0, stream>>>(yn, w2_b, hb, nullptr, b2, nullptr, nullptr, 1024, 256, 2);
    gemm32<<<dim3(128, 4), 256, 0, stream>>>(hb, w3_b, (float*)d_out, b3, mlpin, 256, 1024, 3);
}

// Round 10
// 179.282 us; speedup vs baseline: 1.0340x; 1.0340x over previous
//
#include <hip/hip_runtime.h>
#include <math.h>

#define D 256
#define S 4096
#define H 8
#define DH 32
#define DM 1024
#define NTOK 8192   // B*S

typedef __attribute__((ext_vector_type(8))) short short8;
typedef __attribute__((ext_vector_type(4))) float f32x4;

// qscale = (1/sqrt(32)) * log2(e): folds softmax scale + exp->exp2 into Q
#define QSCALE (0.17677669529663687f * 1.4426950408889634f)

__device__ inline unsigned short f2bf(float f) {
    union { float f; unsigned u; } v; v.f = f;
    unsigned r = v.u + 0x7fffu + ((v.u >> 16) & 1u);
    return (unsigned short)(r >> 16);
}
__device__ inline void gload16(const void* g, void* l) {
    __builtin_amdgcn_global_load_lds((const __attribute__((address_space(1))) void*)g,
                                     (__attribute__((address_space(3))) void*)l, 16, 0, 0);
}

// exp2 + truncate-to-bf16 pack of two f32x4 score vectors into one B-fragment.
// Truncation (not RNE) is fine: the bias cancels between numerator and the
// ones-MFMA denominator, which sums the SAME truncated bf16 P values.
__device__ inline short8 pack_p(f32x4 s0, f32x4 s1) {
    unsigned u0[4], u1[4];
    #pragma unroll
    for (int i = 0; i < 4; ++i) {
        union { float f; unsigned u; } c0, c1;
        c0.f = __builtin_amdgcn_exp2f(s0[i]);
        c1.f = __builtin_amdgcn_exp2f(s1[i]);
        u0[i] = c0.u;
        u1[i] = c1.u;
    }
    union { unsigned u[4]; short8 s; } pk;
    pk.u[0] = __builtin_amdgcn_perm(u0[1], u0[0], 0x07060302u);
    pk.u[1] = __builtin_amdgcn_perm(u0[3], u0[2], 0x07060302u);
    pk.u[2] = __builtin_amdgcn_perm(u1[1], u1[0], 0x07060302u);
    pk.u[3] = __builtin_amdgcn_perm(u1[3], u1[2], 0x07060302u);
    return pk.s;
}

// ---- prep: weights fp32->bf16 + RoPE table + LayerNorm1, ONE launch ----
// blocks 0..3327: conversion/table; blocks 3328..5375: LN1 (1 wave = 1 row).
__global__ void prep(const float* __restrict__ Wq, const float* __restrict__ Wk,
                     const float* __restrict__ Wv, const float* __restrict__ Wo,
                     const float* __restrict__ W2, const float* __restrict__ W3,
                     unsigned short* __restrict__ wqkv, unsigned short* __restrict__ wo_b,
                     unsigned short* __restrict__ w2_b, unsigned short* __restrict__ w3_b,
                     float* __restrict__ ct, float* __restrict__ st,
                     const float* __restrict__ x, const float* __restrict__ g,
                     const float* __restrict__ b, unsigned short* __restrict__ xn) {
    int blk = blockIdx.x;
    if (blk < 3328) {
        int i = blk * 256 + threadIdx.x;           // 0 .. 851967
        if (i < 196608) {
            const float* s = (i < 65536) ? Wq : ((i < 131072) ? Wk : Wv);
            wqkv[i] = f2bf(s[i & 65535]);
        } else if (i < 262144) {
            wo_b[i - 196608] = f2bf(Wo[i - 196608]);
        } else if (i < 524288) {
            w2_b[i - 262144] = f2bf(W2[i - 262144]);
        } else if (i < 786432) {
            w3_b[i - 524288] = f2bf(W3[i - 524288]);
        } else {
            int j = i - 786432;                     // 0 .. 65535
            int spos = j >> 4, pi = j & 15;
            float inv_freq = powf(10000.0f, -(float)(2 * pi) / 32.0f);
            float fr = (float)spos * inv_freq;
            ct[j] = cosf(fr);
            st[j] = sinf(fr);
        }
        return;
    }
    // LayerNorm1: 1 wave = 1 row, float4/lane, no LDS/barriers
    int l = threadIdx.x & 63;
    int row = (blk - 3328) * 4 + (threadIdx.x >> 6);
    const float4 v = *(const float4*)(x + (size_t)row * D + l * 4);
    float s  = v.x + v.y + v.z + v.w;
    float s2 = v.x * v.x + v.y * v.y + v.z * v.z + v.w * v.w;
    #pragma unroll
    for (int off = 32; off > 0; off >>= 1) {
        s  += __shfl_xor(s, off, 64);
        s2 += __shfl_xor(s2, off, 64);
    }
    float mu  = s * (1.0f / D);
    float var = s2 * (1.0f / D) - mu * mu;
    float rs  = rsqrtf(var + 1e-5f);
    const float4 gg = *(const float4*)(g + l * 4);
    const float4 bb = *(const float4*)(b + l * 4);
    ushort4 o;
    o.x = f2bf((v.x - mu) * rs * gg.x + bb.x);
    o.y = f2bf((v.y - mu) * rs * gg.y + bb.y);
    o.z = f2bf((v.z - mu) * rs * gg.z + bb.z);
    o.w = f2bf((v.w - mu) * rs * gg.w + bb.w);
    *(ushort4*)(xn + (size_t)row * D + l * 4) = o;
}

// ---------------- LayerNorm: 1 wave = 1 row, float4/lane (for LN2) ----------------
__global__ void ln_kernel(const float* __restrict__ x, const float* __restrict__ g,
                          const float* __restrict__ b, unsigned short* __restrict__ out) {
    int l = threadIdx.x & 63;
    int row = blockIdx.x * 4 + (threadIdx.x >> 6);
    const float4 v = *(const float4*)(x + (size_t)row * D + l * 4);
    float s  = v.x + v.y + v.z + v.w;
    float s2 = v.x * v.x + v.y * v.y + v.z * v.z + v.w * v.w;
    #pragma unroll
    for (int off = 32; off > 0; off >>= 1) {
        s  += __shfl_xor(s, off, 64);
        s2 += __shfl_xor(s2, off, 64);
    }
    float mu  = s * (1.0f / D);
    float var = s2 * (1.0f / D) - mu * mu;
    float rs  = rsqrtf(var + 1e-5f);
    const float4 gg = *(const float4*)(g + l * 4);
    const float4 bb = *(const float4*)(b + l * 4);
    ushort4 o;
    o.x = f2bf((v.x - mu) * rs * gg.x + bb.x);
    o.y = f2bf((v.y - mu) * rs * gg.y + bb.y);
    o.z = f2bf((v.z - mu) * rs * gg.z + bb.z);
    o.w = f2bf((v.w - mu) * rs * gg.w + bb.w);
    *(ushort4*)(out + (size_t)row * D + l * 4) = o;
}

// ------- bf16 MFMA GEMM, 64x64 tile, BK=64 dbuf (R5-proven for wide-N GEMMs) -------
// R22 lesson: 128x64 tile regressed these K=256 GEMMs (3 blocks/CU vs 6; 4 K-iters
// too short to amortize) — 64x64 with 6 blocks/CU is the sweet spot here.
// modes: 0 = QKV: RoPE+store bf16 for cols<512 (Q cols<256 pre-scaled), cols>=512
//            stored TRANSPOSED to vt[B][H][DH][S];  2 = bf16 store gelu(acc+bias)
__global__ __launch_bounds__(256) void gemm64b(const unsigned short* __restrict__ A,
        const unsigned short* __restrict__ Bw, void* __restrict__ outp,
        unsigned short* __restrict__ vt,
        const float* __restrict__ bias,
        const float* __restrict__ ct, const float* __restrict__ st,
        int N, int K, int mode) {
    __shared__ unsigned short As[2][64 * 64];
    __shared__ unsigned short Bs[2][64 * 64];
    int tid = threadIdx.x;
    int w = tid >> 6, l = tid & 63;
    int lm = l & 15, lg = l >> 4;
    int wm = (w >> 1) * 32, wn = (w & 1) * 32;
    int bm = blockIdx.x * 64, bn = blockIdx.y * 64;
    int r1 = tid >> 3, pc = tid & 7;
    int pcx = (pc ^ (r1 & 7)) * 8;
    const unsigned short* Ag1 = A + (size_t)(bm + r1) * K + pcx;
    const unsigned short* Ag2 = A + (size_t)(bm + 32 + r1) * K + pcx;
    const unsigned short* Bg1 = Bw + (size_t)(bn + r1) * K + pcx;
    const unsigned short* Bg2 = Bw + (size_t)(bn + 32 + r1) * K + pcx;
    const int swz = lm & 7;
    f32x4 acc[2][2] = {};

    gload16(Ag1, &As[0][w * 512]);
    gload16(Ag2, &As[0][2048 + w * 512]);
    gload16(Bg1, &Bs[0][w * 512]);
    gload16(Bg2, &Bs[0][2048 + w * 512]);
    for (int k0 = 0; k0 < K; k0 += 64) {
        int cur = (k0 >> 6) & 1;
        __syncthreads();
        if (k0 + 64 < K) {
            gload16(Ag1 + k0 + 64, &As[1 - cur][w * 512]);
            gload16(Ag2 + k0 + 64, &As[1 - cur][2048 + w * 512]);
            gload16(Bg1 + k0 + 64, &Bs[1 - cur][w * 512]);
            gload16(Bg2 + k0 + 64, &Bs[1 - cur][2048 + w * 512]);
        }
        #pragma unroll
        for (int j = 0; j < 2; ++j) {
            int ch = ((j * 4 + lg) ^ swz) * 8;
            short8 af[2], bf[2];
            #pragma unroll
            for (int i = 0; i < 2; ++i) af[i] = *(const short8*)&As[cur][(wm + i * 16 + lm) * 64 + ch];
            #pragma unroll
            for (int i = 0; i < 2; ++i) bf[i] = *(const short8*)&Bs[cur][(wn + i * 16 + lm) * 64 + ch];
            #pragma unroll
            for (int mi = 0; mi < 2; ++mi)
                #pragma unroll
                for (int ni = 0; ni < 2; ++ni)
                    acc[mi][ni] = __builtin_amdgcn_mfma_f32_16x16x32_bf16(af[mi], bf[ni], acc[mi][ni], 0, 0, 0);
        }
    }

    if (mode == 0) {
        if (bn >= 512) {
            #pragma unroll
            for (int mi = 0; mi < 2; ++mi) {
                #pragma unroll
                for (int ni = 0; ni < 2; ++ni) {
                    int ng = bn + wn + ni * 16 + lm - 512;   // h*32+dh
                    int hh = ng >> 5, dh = ng & 31;
                    int mg0 = bm + wm + mi * 16 + lg * 4;
                    int bbx = mg0 >> 12, ss = mg0 & 4095;
                    ushort4 pv;
                    pv.x = f2bf(acc[mi][ni][0]); pv.y = f2bf(acc[mi][ni][1]);
                    pv.z = f2bf(acc[mi][ni][2]); pv.w = f2bf(acc[mi][ni][3]);
                    *(ushort4*)(vt + ((size_t)((bbx * 8 + hh) * 32 + dh)) * S + ss) = pv;
                }
            }
        } else {
            #pragma unroll
            for (int mi = 0; mi < 2; ++mi) {
                #pragma unroll
                for (int ni = 0; ni < 2; ++ni) {
                    int ng = bn + wn + ni * 16 + lm;
                    int pi = (ng & 31) >> 1;
                    float sgn = (ng & 1) ? 1.f : -1.f;
                    float qs  = (ng < 256) ? QSCALE : 1.f;
                    #pragma unroll
                    for (int r2 = 0; r2 < 4; ++r2) {
                        int mg = bm + wm + mi * 16 + lg * 4 + r2;
                        int spos = mg & (S - 1);
                        float vv = acc[mi][ni][r2];
                        float pv = __shfl_xor(vv, 1, 64);
                        float cs = ct[spos * 16 + pi];
                        float sn = st[spos * 16 + pi];
                        float ov = (vv * cs + sgn * pv * sn) * qs;
                        ((unsigned short*)outp)[(size_t)mg * N + ng] = f2bf(ov);
                    }
                }
            }
        }
        return;
    }
    // mode 2: gelu(acc+bias), bf16 store
    #pragma unroll
    for (int mi = 0; mi < 2; ++mi) {
        #pragma unroll
        for (int ni = 0; ni < 2; ++ni) {
            int ng = bn + wn + ni * 16 + lm;
            #pragma unroll
            for (int r2 = 0; r2 < 4; ++r2) {
                int mg = bm + wm + mi * 16 + lg * 4 + r2;
                float t = acc[mi][ni][r2] + bias[ng];
                ((unsigned short*)outp)[(size_t)mg * N + ng] =
                    f2bf(0.5f * t * (1.0f + erff(t * 0.70710678118654752f)));
            }
        }
    }
}

// ------- bf16 MFMA GEMM v2, 64x64 tile, BK=128 dbuf: for the N=256 GEMMs -------
// R21 (validated, -7us e2e): 4 waves, per-wave 32x32 acc[2][2]: 4 reads : 4 MFMA.
// R25 lesson (REVERTED): porting attn's 3-buf counted-vmcnt here regressed -4us —
// BK=64 doubles barrier count while 2-block/CU overlap already hides the dbuf's
// vmcnt(0) drains (short per-step dep chain, unlike attn). Keep BK=128 dbuf.
// modes: 1 = fp32 store acc+res; 3 = fp32 store acc+bias+res
__global__ __launch_bounds__(256) void gemm32(const unsigned short* __restrict__ A,
        const unsigned short* __restrict__ Bw, void* __restrict__ outp,
        const float* __restrict__ bias, const float* __restrict__ res,
        int N, int K, int mode) {
    __shared__ unsigned short As[2][64 * 128];
    __shared__ unsigned short Bs[2][64 * 128];
    int tid = threadIdx.x;
    int w = tid >> 6, l = tid & 63;
    int lm = l & 15, lg = l >> 4;
    int wm = (w >> 1) * 32, wn = (w & 1) * 32;
    int bm = blockIdx.x * 64, bn = blockIdx.y * 64;
    int r1 = tid >> 4, pc = tid & 15;
    int pcx = (pc ^ (r1 & 7)) * 8;
    const unsigned short* Ag1 = A + (size_t)(bm + r1) * K + pcx;
    const unsigned short* Ag2 = A + (size_t)(bm + 16 + r1) * K + pcx;
    const unsigned short* Ag3 = A + (size_t)(bm + 32 + r1) * K + pcx;
    const unsigned short* Ag4 = A + (size_t)(bm + 48 + r1) * K + pcx;
    const unsigned short* Bg1 = Bw + (size_t)(bn + r1) * K + pcx;
    const unsigned short* Bg2 = Bw + (size_t)(bn + 16 + r1) * K + pcx;
    const unsigned short* Bg3 = Bw + (size_t)(bn + 32 + r1) * K + pcx;
    const unsigned short* Bg4 = Bw + (size_t)(bn + 48 + r1) * K + pcx;
    const int swz = lm & 7;
    f32x4 acc[2][2] = {};

    gload16(Ag1, &As[0][w * 512]);
    gload16(Ag2, &As[0][2048 + w * 512]);
    gload16(Ag3, &As[0][4096 + w * 512]);
    gload16(Ag4, &As[0][6144 + w * 512]);
    gload16(Bg1, &Bs[0][w * 512]);
    gload16(Bg2, &Bs[0][2048 + w * 512]);
    gload16(Bg3, &Bs[0][4096 + w * 512]);
    gload16(Bg4, &Bs[0][6144 + w * 512]);
    for (int k0 = 0; k0 < K; k0 += 128) {
        int cur = (k0 >> 7) & 1;
        __syncthreads();
        if (k0 + 128 < K) {
            gload16(Ag1 + k0 + 128, &As[1 - cur][w * 512]);
            gload16(Ag2 + k0 + 128, &As[1 - cur][2048 + w * 512]);
            gload16(Ag3 + k0 + 128, &As[1 - cur][4096 + w * 512]);
            gload16(Ag4 + k0 + 128, &As[1 - cur][6144 + w * 512]);
            gload16(Bg1 + k0 + 128, &Bs[1 - cur][w * 512]);
            gload16(Bg2 + k0 + 128, &Bs[1 - cur][2048 + w * 512]);
            gload16(Bg3 + k0 + 128, &Bs[1 - cur][4096 + w * 512]);
            gload16(Bg4 + k0 + 128, &Bs[1 - cur][6144 + w * 512]);
        }
        #pragma unroll
        for (int j = 0; j < 4; ++j) {
            int ch = ((j * 4 + lg) ^ swz) * 8;
            short8 af[2], bf[2];
            #pragma unroll
            for (int i = 0; i < 2; ++i) af[i] = *(const short8*)&As[cur][(wm + i * 16 + lm) * 128 + ch];
            #pragma unroll
            for (int i = 0; i < 2; ++i) bf[i] = *(const short8*)&Bs[cur][(wn + i * 16 + lm) * 128 + ch];
            #pragma unroll
            for (int mi = 0; mi < 2; ++mi)
                #pragma unroll
                for (int ni = 0; ni < 2; ++ni)
                    acc[mi][ni] = __builtin_amdgcn_mfma_f32_16x16x32_bf16(af[mi], bf[ni], acc[mi][ni], 0, 0, 0);
        }
    }

    #pragma unroll
    for (int mi = 0; mi < 2; ++mi) {
        #pragma unroll
        for (int ni = 0; ni < 2; ++ni) {
            int ng = bn + wn + ni * 16 + lm;
            #pragma unroll
            for (int r2 = 0; r2 < 4; ++r2) {
                int mg = bm + wm + mi * 16 + lg * 4 + r2;
                float v = acc[mi][ni][r2];
                size_t idx = (size_t)mg * N + ng;
                if (mode == 1) {
                    ((float*)outp)[idx] = v + res[idx];
                } else {
                    ((float*)outp)[idx] = v + bias[ng] + res[idx];
                }
            }
        }
    }
}

// -------- MFMA flash attention: R19 structure + cross-half pipelining (R24) ------
// Pinned at 48.0-48.1us across 7 structural variants (R19/R23/R24 etc);
// MfmaUtil+VALUBusy ~80% combined — structural floor for this decomposition.
// R23 lesson: more occupancy does NOT help (split-key x4 +45% waves = net worse).
// R20 lesson: LDS staging via global_load_lds DMA is the transaction-efficient
// shape; per-lane fragment gathers split ~16x.
__global__ __launch_bounds__(512, 4) void attn_kernel(const unsigned short* __restrict__ Cq,
        const unsigned short* __restrict__ vt, unsigned short* __restrict__ out) {
    __shared__ unsigned short Ks[2][3][64][32];  // [grp][buf][phys key row][dim] 24KB
    __shared__ unsigned short Vs[2][3][32][64];  // [grp][buf][dim][key]          24KB
    int tid = threadIdx.x;
    int w = tid >> 6, l = tid & 63;
    int grp = w >> 2, ws = w & 3;
    int lm = l & 15, lg = l >> 4;
    int qt = blockIdx.x >> 4;                    // XCD-cluster swizzle
    int bh = blockIdx.x & 15;
    int bb = bh >> 3, h = bh & 7;
    int q0 = qt * 128 + ws * 32;                 // 32 q rows per wave

    const short8 qfa = *(const short8*)(Cq + ((size_t)(bb * S + q0 + lm)) * 768 + h * DH + lg * 8);
    const short8 qfb = *(const short8*)(Cq + ((size_t)(bb * S + q0 + 16 + lm)) * 768 + h * DH + lg * 8);

    // ones A-fragment in registers: A row 0 = 1.0 -> lanes with lm==0, any k-col
    union { unsigned short us[8]; short8 s; } onesu;
    {
        unsigned short ov = (lm == 0) ? (unsigned short)0x3F80 : (unsigned short)0;
        #pragma unroll
        for (int i = 0; i < 8; ++i) onesu.us[i] = ov;
    }
    const short8 onef = onesu.s;

    int p = ws * 16 + (l >> 2);
    int krow = ((p >> 5) << 5) + (((p >> 2) & 3) << 3) + (((p >> 4) & 1) << 2) + (p & 3);
    const unsigned short* kg = Cq + ((size_t)(bb * S)) * 768 + 256 + h * 32
                               + (size_t)krow * 768 + ((l & 3) ^ ((l >> 3) & 3)) * 8;
    const unsigned short* vg = vt + ((size_t)(bh * 32 + ws * 8 + (l >> 3))) * S + ((l & 7) ^ (l >> 3)) * 8;
    const int kswz = (lm >> 1) & 3;
    const int vswz = lm & 7;

    f32x4 o0a = {0.f, 0.f, 0.f, 0.f}, o1a = {0.f, 0.f, 0.f, 0.f}, o2a = {0.f, 0.f, 0.f, 0.f};
    f32x4 o0b = {0.f, 0.f, 0.f, 0.f}, o1b = {0.f, 0.f, 0.f, 0.f}, o2b = {0.f, 0.f, 0.f, 0.f};
    const f32x4 z = {0.f, 0.f, 0.f, 0.f};

    // depth-2 prologue: tiles grp -> buf0, 2+grp -> buf1 (K,V per tile; 4 loads)
    gload16(kg + (size_t)grp * 64 * 768,       &Ks[grp][0][ws * 16][0]);
    gload16(vg + (size_t)grp * 64,             &Vs[grp][0][ws * 8][0]);
    gload16(kg + (size_t)(2 + grp) * 64 * 768, &Ks[grp][1][ws * 16][0]);
    gload16(vg + (size_t)(2 + grp) * 64,       &Vs[grp][1][ws * 8][0]);
    // fence: Q register loads retired; exactly 4 stage loads outstanding
    asm volatile("s_waitcnt vmcnt(4)" ::: "memory");

#define ATTN_STEP(J, CUR, NXT) do {                                                          \
    asm volatile("s_waitcnt vmcnt(2) lgkmcnt(0)" ::: "memory");                              \
    __builtin_amdgcn_s_barrier();                                                            \
    __builtin_amdgcn_sched_barrier(0);                                                       \
    int tt_ = (J) + 2; if (tt_ > 31) tt_ = 31;                                               \
    size_t tg_ = (size_t)(2 * tt_ + grp);                                                    \
    gload16(kg + tg_ * 64 * 768, &Ks[grp][NXT][ws * 16][0]);                                 \
    gload16(vg + tg_ * 64,       &Vs[grp][NXT][ws * 8][0]);                                  \
    short8 kf0 = *(const short8*)&Ks[grp][CUR][lm][(lg ^ kswz) * 8];                         \
    short8 kf1 = *(const short8*)&Ks[grp][CUR][16 + lm][(lg ^ kswz) * 8];                    \
    short8 kf2 = *(const short8*)&Ks[grp][CUR][32 + lm][(lg ^ kswz) * 8];                    \
    short8 kf3 = *(const short8*)&Ks[grp][CUR][48 + lm][(lg ^ kswz) * 8];                    \
    __builtin_amdgcn_s_setprio(1);                                                           \
    f32x4 s0a = __builtin_amdgcn_mfma_f32_16x16x32_bf16(kf0, qfa, z, 0, 0, 0);               \
    f32x4 s1a = __builtin_amdgcn_mfma_f32_16x16x32_bf16(kf1, qfa, z, 0, 0, 0);               \
    f32x4 s0b = __builtin_amdgcn_mfma_f32_16x16x32_bf16(kf0, qfb, z, 0, 0, 0);               \
    f32x4 s1b = __builtin_amdgcn_mfma_f32_16x16x32_bf16(kf1, qfb, z, 0, 0, 0);               \
    f32x4 t0a = __builtin_amdgcn_mfma_f32_16x16x32_bf16(kf2, qfa, z, 0, 0, 0);               \
    f32x4 t1a = __builtin_amdgcn_mfma_f32_16x16x32_bf16(kf3, qfa, z, 0, 0, 0);               \
    f32x4 t0b = __builtin_amdgcn_mfma_f32_16x16x32_bf16(kf2, qfb, z, 0, 0, 0);               \
    f32x4 t1b = __builtin_amdgcn_mfma_f32_16x16x32_bf16(kf3, qfb, z, 0, 0, 0);               \
    __builtin_amdgcn_s_setprio(0);                                                           \
    short8 pfa = pack_p(s0a, s1a);                                                           \
    short8 pfb = pack_p(s0b, s1b);                                                           \
    int vc0 = (lg ^ vswz) * 8;                                                               \
    short8 va0 = *(const short8*)&Vs[grp][CUR][lm][vc0];                                     \
    short8 va1 = *(const short8*)&Vs[grp][CUR][16 + lm][vc0];                                \
    __builtin_amdgcn_s_setprio(1);                                                           \
    o0a = __builtin_amdgcn_mfma_f32_16x16x32_bf16(va0, pfa, o0a, 0, 0, 0);                   \
    o1a = __builtin_amdgcn_mfma_f32_16x16x32_bf16(va1, pfa, o1a, 0, 0, 0);                   \
    o2a = __builtin_amdgcn_mfma_f32_16x16x32_bf16(onef, pfa, o2a, 0, 0, 0);                  \
    o0b = __builtin_amdgcn_mfma_f32_16x16x32_bf16(va0, pfb, o0b, 0, 0, 0);                   \
    o1b = __builtin_amdgcn_mfma_f32_16x16x32_bf16(va1, pfb, o1b, 0, 0, 0);                   \
    o2b = __builtin_amdgcn_mfma_f32_16x16x32_bf16(onef, pfb, o2b, 0, 0, 0);                  \
    __builtin_amdgcn_s_setprio(0);                                                           \
    short8 pfa2 = pack_p(t0a, t1a);                                                          \
    short8 pfb2 = pack_p(t0b, t1b);                                                          \
    int vc1 = ((4 + lg) ^ vswz) * 8;                                                         \
    short8 vb0 = *(const short8*)&Vs[grp][CUR][lm][vc1];                                     \
    short8 vb1 = *(const short8*)&Vs[grp][CUR][16 + lm][vc1];                                \
    __builtin_amdgcn_s_setprio(1);                                                           \
    o0a = __builtin_amdgcn_mfma_f32_16x16x32_bf16(vb0, pfa2, o0a, 0, 0, 0);                  \
    o1a = __builtin_amdgcn_mfma_f32_16x16x32_bf16(vb1, pfa2, o1a, 0, 0, 0);                  \
    o2a = __builtin_amdgcn_mfma_f32_16x16x32_bf16(onef, pfa2, o2a, 0, 0, 0);                 \
    o0b = __builtin_amdgcn_mfma_f32_16x16x32_bf16(vb0, pfb2, o0b, 0, 0, 0);                  \
    o1b = __builtin_amdgcn_mfma_f32_16x16x32_bf16(vb1, pfb2, o1b, 0, 0, 0);                  \
    o2b = __builtin_amdgcn_mfma_f32_16x16x32_bf16(onef, pfb2, o2b, 0, 0, 0);                 \
    __builtin_amdgcn_s_setprio(0);                                                           \
} while (0)

    for (int j3 = 0; j3 < 30; j3 += 3) {
        ATTN_STEP(j3,     0, 2);
        ATTN_STEP(j3 + 1, 1, 0);
        ATTN_STEP(j3 + 2, 2, 1);
    }
    ATTN_STEP(30, 0, 2);
    ATTN_STEP(31, 1, 0);
#undef ATTN_STEP

    // cross-group combine via LDS aliased onto the (now dead) staging buffers
    f32x4* Red = (f32x4*)&Ks[0][0][0][0];   // 4acc x 4ws x 64l x 16B = 16KB (of 24KB)
    float* Den = (float*)&Vs[0][0][0][0];   // 4ws x 2 x 64l x 4B = 2KB
    __syncthreads();                        // drains dummy prefetches too (vmcnt 0)
    if (grp) {
        Red[(0 * 4 + ws) * 64 + l] = o0a;
        Red[(1 * 4 + ws) * 64 + l] = o1a;
        Red[(2 * 4 + ws) * 64 + l] = o0b;
        Red[(3 * 4 + ws) * 64 + l] = o1b;
        Den[(ws * 2 + 0) * 64 + l] = o2a[0];
        Den[(ws * 2 + 1) * 64 + l] = o2b[0];
    }
    __syncthreads();
    if (!grp) {
        f32x4 a0 = Red[(0 * 4 + ws) * 64 + l];
        f32x4 a1 = Red[(1 * 4 + ws) * 64 + l];
        f32x4 a2 = Red[(2 * 4 + ws) * 64 + l];
        f32x4 a3 = Red[(3 * 4 + ws) * 64 + l];
        float dda = o2a[0] + Den[(ws * 2 + 0) * 64 + l];
        float ddb = o2b[0] + Den[(ws * 2 + 1) * 64 + l];
        #pragma unroll
        for (int i = 0; i < 4; ++i) {
            o0a[i] += a0[i]; o1a[i] += a1[i];
            o0b[i] += a2[i]; o1b[i] += a3[i];
        }
        float inva = 1.0f / __shfl(dda, lm, 64);
        float invb = 1.0f / __shfl(ddb, lm, 64);
        ushort4 r0, r1;
        r0.x = f2bf(o0a[0] * inva); r0.y = f2bf(o0a[1] * inva);
        r0.z = f2bf(o0a[2] * inva); r0.w = f2bf(o0a[3] * inva);
        r1.x = f2bf(o1a[0] * inva); r1.y = f2bf(o1a[1] * inva);
        r1.z = f2bf(o1a[2] * inva); r1.w = f2bf(o1a[3] * inva);
        unsigned short* ob = out + ((size_t)(bb * S + q0 + lm)) * D + h * DH;
        *(ushort4*)(ob + lg * 4)      = r0;
        *(ushort4*)(ob + 16 + lg * 4) = r1;
        r0.x = f2bf(o0b[0] * invb); r0.y = f2bf(o0b[1] * invb);
        r0.z = f2bf(o0b[2] * invb); r0.w = f2bf(o0b[3] * invb);
        r1.x = f2bf(o1b[0] * invb); r1.y = f2bf(o1b[1] * invb);
        r1.z = f2bf(o1b[2] * invb); r1.w = f2bf(o1b[3] * invb);
        unsigned short* ob2 = out + ((size_t)(bb * S + q0 + 16 + lm)) * D + h * DH;
        *(ushort4*)(ob2 + lg * 4)      = r0;
        *(ushort4*)(ob2 + 16 + lg * 4) = r1;
    }
}

extern "C" void kernel_launch(void* const* d_in, const int* in_sizes, int n_in,
                              void* d_out, int out_size, void* d_ws, size_t ws_size,
                              hipStream_t stream) {
    const float* x     = (const float*)d_in[0];
    const float* Wq    = (const float*)d_in[1];
    const float* Wk    = (const float*)d_in[2];
    const float* Wv    = (const float*)d_in[3];
    const float* Wo    = (const float*)d_in[4];
    const float* ln1_g = (const float*)d_in[5];
    const float* ln1_b = (const float*)d_in[6];
    const float* ln2_g = (const float*)d_in[7];
    const float* ln2_b = (const float*)d_in[8];
    const float* W2    = (const float*)d_in[9];
    const float* b2    = (const float*)d_in[10];
    const float* W3    = (const float*)d_in[11];
    const float* b3    = (const float*)d_in[12];

    char* w8 = (char*)d_ws;
    unsigned short* wqkv = (unsigned short*)(w8);             // 196608 ush
    unsigned short* wo_b = (unsigned short*)(w8 + 393216);    // 65536
    unsigned short* w2_b = (unsigned short*)(w8 + 524288);    // 262144
    unsigned short* w3_b = (unsigned short*)(w8 + 1048576);   // 262144
    float*          ct   = (float*)(w8 + 1572864);            // 65536 f32
    float*          st   = (float*)(w8 + 1835008);            // 65536 f32
    unsigned short* xn   = (unsigned short*)(w8 + 2097152);   // 2M ush (reused as yn)
    unsigned short* Cq   = (unsigned short*)(w8 + 6291456);   // 6.29M ush (QKV out)
    unsigned short* hb   = Cq;                                // MLP hidden reuses (16MB)
    unsigned short* vtb  = (unsigned short*)(w8 + 23068672);  // 2M ush
    unsigned short* ab   = (unsigned short*)(w8 + 27262976);  // 2M ush
    float*          mlpin= (float*)(w8 + 31457280);           // 2M f32
    unsigned short* yn   = xn;

    prep<<<5376, 256, 0, stream>>>(Wq, Wk, Wv, Wo, W2, W3, wqkv, wo_b, w2_b, w3_b,
                                   ct, st, x, ln1_g, ln1_b, xn);
    gemm64b<<<dim3(128, 12), 256, 0, stream>>>(xn, wqkv, Cq, vtb, nullptr, ct, st, 768, 256, 0);
    attn_kernel<<<512, 512, 0, stream>>>(Cq, vtb, ab);
    gemm32<<<dim3(128, 4), 256, 0, stream>>>(ab, wo_b, mlpin, nullptr, x, 256, 256, 1);
    ln_kernel<<<NTOK / 4, 256, 0, stream>>>(mlpin, ln2_g, ln2_b, yn);
    gemm64b<<<dim3(128, 16), 256, 0, stream>>>(yn, w2_b, hb, nullptr, b2, nullptr, nullptr, 1024, 256, 2);
    gemm32<<<dim3(128, 4), 256, 0, stream>>>(hb, w3_b, (float*)d_out, b3, mlpin, 256, 1024, 3);
}